// Round 1
// baseline (368.070 us; speedup 1.0000x reference)
//
#include <hip/hip_runtime.h>
#include <hip/hip_bf16.h>

#define H0 480
#define W0 640
#define H1 240
#define W1 320
#define H2 120
#define W2 160
#define H3 60
#define W3 80

// fp32 weight buffer offsets (in floats) inside d_ws  (transposed pointwise copies)
#define W_PW1T  0      // 5*32  [cin*32+o]
#define W_PW2T  160    // 32*64 [cin*64+o]
#define W_PW3T  2208   // 64*64 [cin*64+o]
#define WBUF_BYTES 65536

#define F2_PB (64 * H2 * W2)   // 1,228,800
#define F3_PB (64 * H3 * W3)   //   307,200

typedef float v2f __attribute__((ext_vector_type(2)));

// ---------------- K0: transpose pointwise weights ---------------------------
__global__ __launch_bounds__(256) void k_cvt(
    const float* __restrict__ pw1, const float* __restrict__ pw2,
    const float* __restrict__ pw3, float* __restrict__ wb)
{
    int t = threadIdx.x;
    for (int i = t; i < 160;  i += 256) { int o = i / 5,  c = i % 5;  wb[W_PW1T + c*32 + o] = pw1[i]; }
    for (int i = t; i < 2048; i += 256) { int o = i >> 5, c = i & 31; wb[W_PW2T + c*64 + o] = pw2[i]; }
    for (int i = t; i < 4096; i += 256) { int o = i >> 6, c = i & 63; wb[W_PW3T + c*64 + o] = pw3[i]; }
}

// ---------------- K12: fused stage1+stage2, register-direct (no LDS) ---------
// Thread remap packs interior pixels (oh>=1, ow>=1) into contiguous waves:
// per batch 19200 threads = 300 waves; 296 run the mask-free fast path
// (closed-form coord convs, const-offset loads, packed-fp32 pw2 update),
// ~4-5 waves run the general boundary path.
__global__ __launch_bounds__(256, 3) void k_fuse12(
    const float* __restrict__ flow, const float* __restrict__ dw1,
    const float* __restrict__ b1, const float* __restrict__ dw2,
    const float* __restrict__ b2, const float* __restrict__ wb,
    float* __restrict__ out)
{
    int idx = blockIdx.x * 256 + threadIdx.x;     // 614,400 exact
    int t = idx % (H2*W2); int b = idx / (H2*W2);
    const float sy = 2.f / (H0 - 1), sx = 2.f / (W0 - 1);
    const int NI = (H2-1) * (W2-1);               // 119*159 = 18921 interior

    if (t < NI) {
        // ---------------- interior fast path ----------------
        int oh = 1 + t / (W2-1), ow = 1 + t % (W2-1);
        float d[9][5];

        // flow channels: 7x7 unique input window, compile-time offsets
        {
            const float* a0 = flow + ((size_t)(b*2)) * (H0*W0)
                              + (size_t)(4*oh - 3) * W0 + (4*ow - 3);
            #pragma unroll
            for (int c = 0; c < 2; c++) {
                const float* ap = a0 + (size_t)c * (H0*W0);
                float w[7][7];
                #pragma unroll
                for (int r7 = 0; r7 < 7; r7++)
                    #pragma unroll
                    for (int k = 0; k < 7; k++)
                        w[r7][k] = ap[r7*W0 + k];
                #pragma unroll
                for (int r = 0; r < 3; r++)
                    #pragma unroll
                    for (int s = 0; s < 3; s++) {
                        float a = 0.f;
                        #pragma unroll
                        for (int ky = 0; ky < 3; ky++)
                            #pragma unroll
                            for (int kx = 0; kx < 3; kx++)
                                a = fmaf(dw1[c*9 + ky*3 + kx], w[2*r+ky][2*s+kx], a);
                        d[r*3+s][c] = a;
                    }
            }
        }

        // coord channels: closed form (separable; conv of linear/quadratic field)
        {
            float cs2[3], rs3[3], cs4[3], rs4[3];       // uniform col/row sums of dw1
            #pragma unroll
            for (int k = 0; k < 3; k++) {
                cs2[k] = dw1[18+k]   + dw1[21+k]   + dw1[24+k];
                rs3[k] = dw1[27+3*k] + dw1[28+3*k] + dw1[29+3*k];
                cs4[k] = dw1[36+k]   + dw1[39+k]   + dw1[42+k];
                rs4[k] = dw1[36+3*k] + dw1[37+3*k] + dw1[38+3*k];
            }
            float u[7], vv7[7], u2[7], v2a[7];
            float ub = fmaf((float)(4*ow - 3), sx, -1.f);
            float vb = fmaf((float)(4*oh - 3), sy, -1.f);
            #pragma unroll
            for (int m = 0; m < 7; m++) {
                u[m]   = fmaf((float)m, sx, ub);
                vv7[m] = fmaf((float)m, sy, vb);
                u2[m]  = u[m]*u[m];
                v2a[m] = vv7[m]*vv7[m];
            }
            float axs[3], arx[3], ays[3], ary[3];
            #pragma unroll
            for (int s = 0; s < 3; s++) {
                float ax = 0.f, gx = 0.f;
                #pragma unroll
                for (int kx = 0; kx < 3; kx++) {
                    ax = fmaf(cs2[kx], u[2*s+kx],  ax);
                    gx = fmaf(cs4[kx], u2[2*s+kx], gx);
                }
                axs[s] = ax; arx[s] = gx;
            }
            #pragma unroll
            for (int r = 0; r < 3; r++) {
                float ay = 0.f, gy = 0.f;
                #pragma unroll
                for (int ky = 0; ky < 3; ky++) {
                    ay = fmaf(rs3[ky], vv7[2*r+ky], ay);
                    gy = fmaf(rs4[ky], v2a[2*r+ky], gy);
                }
                ays[r] = ay; ary[r] = gy;
            }
            #pragma unroll
            for (int r = 0; r < 3; r++)
                #pragma unroll
                for (int s = 0; s < 3; s++) {
                    d[r*3+s][2] = axs[s];
                    d[r*3+s][3] = ays[r];
                    d[r*3+s][4] = arx[s] + ary[r];
                }
        }

        v2f acc2[32];
        #pragma unroll
        for (int o = 0; o < 32; o++) acc2[o] = *(const v2f*)(b2 + 2*o);

        for (int c = 0; c < 32; c++) {
            const float* w1 = wb + W_PW1T + c;
            float w10 = w1[0], w11 = w1[32], w12 = w1[64], w13 = w1[96], w14 = w1[128];
            float bc = b1[c];
            const float* w9 = dw2 + c*9;               // uniform
            float dv = 0.f;
            #pragma unroll
            for (int p = 0; p < 9; p++) {
                float vv = bc;
                vv = fmaf(w10, d[p][0], vv);
                vv = fmaf(w11, d[p][1], vv);
                vv = fmaf(w12, d[p][2], vv);
                vv = fmaf(w13, d[p][3], vv);
                vv = fmaf(w14, d[p][4], vv);
                float f1v = vv > 0.f ? vv : (__expf(vv) - 1.f);
                dv = fmaf(w9[p], f1v, dv);             // no vm: interior
            }
            const v2f* wr2 = (const v2f*)(wb + W_PW2T + c*64);
            v2f dvv = { dv, dv };
            #pragma unroll
            for (int o = 0; o < 32; o++)
                acc2[o] = __builtin_elementwise_fma(wr2[o], dvv, acc2[o]);  // v_pk_fma_f32
        }

        size_t obase = ((size_t)b * 64) * (H2*W2) + (size_t)oh*W2 + ow;
        #pragma unroll
        for (int o = 0; o < 32; o++) {
            float va = acc2[o].x, vb2 = acc2[o].y;
            out[obase + (size_t)(2*o)  *(H2*W2)] = va  > 0.f ? va  : (__expf(va)  - 1.f);
            out[obase + (size_t)(2*o+1)*(H2*W2)] = vb2 > 0.f ? vb2 : (__expf(vb2) - 1.f);
        }
        return;
    }

    // ---------------- boundary path (oh==0 || ow==0): original general code ----
    {
        int s2 = t - NI;
        int oh, ow;
        if (s2 < W2) { oh = 0; ow = s2; } else { oh = s2 - (W2-1); ow = 0; }

        int fh0 = 2*oh - 1, fw0 = 2*ow - 1;

        float d[9][5];
        float vm[9];

        #pragma unroll
        for (int r = 0; r < 3; r++) {
            #pragma unroll
            for (int s = 0; s < 3; s++) {
                int p = r*3 + s;
                int fh = fh0 + r, fw = fw0 + s;
                vm[p] = (fh >= 0 && fw >= 0) ? 1.f : 0.f;
                int fhc = fh < 0 ? 0 : fh, fwc = fw < 0 ? 0 : fw;
                int ih0 = 2*fhc - 1, iw0 = 2*fwc - 1;
                float mh[3] = { ih0 >= 0 ? 1.f : 0.f, 1.f, 1.f };
                float mw[3] = { iw0 >= 0 ? 1.f : 0.f, 1.f, 1.f };
                int ihx[3] = { ih0 < 0 ? 0 : ih0, ih0 + 1, ih0 + 2 };
                int iwx[3] = { iw0 < 0 ? 0 : iw0, iw0 + 1, iw0 + 2 };

                #pragma unroll
                for (int c = 0; c < 2; c++) {
                    const float* base = flow + ((size_t)(b*2 + c)) * (H0*W0);
                    float a = 0.f;
                    #pragma unroll
                    for (int ky = 0; ky < 3; ky++) {
                        const float* rp = base + (size_t)ihx[ky] * W0;
                        #pragma unroll
                        for (int kx = 0; kx < 3; kx++)
                            a = fmaf(dw1[c*9 + ky*3 + kx], (mh[ky]*mw[kx]) * rp[iwx[kx]], a);
                    }
                    d[p][c] = a;
                }
                float ax = 0.f, ay = 0.f, ar = 0.f;
                #pragma unroll
                for (int ky = 0; ky < 3; ky++) {
                    float yv = fmaf((float)(ih0 + ky), sy, -1.f);
                    #pragma unroll
                    for (int kx = 0; kx < 3; kx++) {
                        float xv = fmaf((float)(iw0 + kx), sx, -1.f);
                        float m = mh[ky] * mw[kx];
                        ax = fmaf(dw1[18 + ky*3 + kx], m * xv, ax);
                        ay = fmaf(dw1[27 + ky*3 + kx], m * yv, ay);
                        ar = fmaf(dw1[36 + ky*3 + kx], m * (xv*xv + yv*yv), ar);
                    }
                }
                d[p][2] = ax; d[p][3] = ay; d[p][4] = ar;
            }
        }

        float acc[64];
        #pragma unroll
        for (int o = 0; o < 64; o++) acc[o] = b2[o];

        for (int c = 0; c < 32; c++) {
            const float* w1 = wb + W_PW1T + c;
            float w10 = w1[0], w11 = w1[32], w12 = w1[64], w13 = w1[96], w14 = w1[128];
            float bc = b1[c];
            const float* w9 = dw2 + c*9;
            float dv = 0.f;
            #pragma unroll
            for (int p = 0; p < 9; p++) {
                float v = bc;
                v = fmaf(w10, d[p][0], v);
                v = fmaf(w11, d[p][1], v);
                v = fmaf(w12, d[p][2], v);
                v = fmaf(w13, d[p][3], v);
                v = fmaf(w14, d[p][4], v);
                float f1v = v > 0.f ? v : (__expf(v) - 1.f);
                dv = fmaf(w9[p], f1v * vm[p], dv);
            }
            const float* wr = wb + W_PW2T + c*64;
            #pragma unroll
            for (int o = 0; o < 64; o++) acc[o] = fmaf(wr[o], dv, acc[o]);
        }

        size_t obase = ((size_t)b * 64) * (H2*W2) + (size_t)oh*W2 + ow;
        #pragma unroll
        for (int o = 0; o < 64; o++) {
            float v = acc[o];
            out[obase + (size_t)o*(H2*W2)] = v > 0.f ? v : (__expf(v) - 1.f);
        }
    }
}

// ---------------- K3: dwsep3 + ELU, register-direct (no LDS) -----------------
// Same interior/boundary remap: 4800 threads/batch = 75 waves, 73 fast.
__global__ __launch_bounds__(256, 4) void k_stage3(
    const float* __restrict__ in, const float* __restrict__ dw3,
    const float* __restrict__ b3, const float* __restrict__ wb,
    float* __restrict__ out)
{
    int idx = blockIdx.x * 256 + threadIdx.x;     // 153,600 exact
    int t = idx % (H3*W3); int b = idx / (H3*W3);
    const int NI = (H3-1) * (W3-1);               // 59*79 = 4661 interior

    if (t < NI) {
        int oh = 1 + t / (W3-1), ow = 1 + t % (W3-1);

        v2f acc2[32];
        #pragma unroll
        for (int o = 0; o < 32; o++) acc2[o] = *(const v2f*)(b3 + 2*o);

        const float* inb = in + (size_t)b * F2_PB + (size_t)(2*oh - 1)*W2 + (2*ow - 1);
        for (int c = 0; c < 64; c++) {
            const float* g = inb + (size_t)c * (H2*W2);
            const float* w9 = dw3 + c*9;           // uniform
            float dv = 0.f;
            #pragma unroll
            for (int ky = 0; ky < 3; ky++)
                #pragma unroll
                for (int kx = 0; kx < 3; kx++)
                    dv = fmaf(w9[ky*3 + kx], g[ky*W2 + kx], dv);   // const offsets
            const v2f* wr2 = (const v2f*)(wb + W_PW3T + c*64);
            v2f dvv = { dv, dv };
            #pragma unroll
            for (int o = 0; o < 32; o++)
                acc2[o] = __builtin_elementwise_fma(wr2[o], dvv, acc2[o]);  // v_pk_fma_f32
        }

        size_t obase = ((size_t)b * 64) * (H3*W3) + (size_t)oh*W3 + ow;
        #pragma unroll
        for (int o = 0; o < 32; o++) {
            float va = acc2[o].x, vb2 = acc2[o].y;
            out[obase + (size_t)(2*o)  *(H3*W3)] = va  > 0.f ? va  : (__expf(va)  - 1.f);
            out[obase + (size_t)(2*o+1)*(H3*W3)] = vb2 > 0.f ? vb2 : (__expf(vb2) - 1.f);
        }
        return;
    }

    // boundary path: original general code
    {
        int s2 = t - NI;
        int oh, ow;
        if (s2 < W3) { oh = 0; ow = s2; } else { oh = s2 - (W3-1); ow = 0; }

        int ih0 = 2*oh - 1, iw0 = 2*ow - 1;
        float mh[3] = { ih0 >= 0 ? 1.f : 0.f, 1.f, 1.f };
        float mw[3] = { iw0 >= 0 ? 1.f : 0.f, 1.f, 1.f };
        int ihx[3] = { ih0 < 0 ? 0 : ih0, ih0 + 1, ih0 + 2 };
        int iwx[3] = { iw0 < 0 ? 0 : iw0, iw0 + 1, iw0 + 2 };
        float m9[9];
        int off[9];
        #pragma unroll
        for (int ky = 0; ky < 3; ky++)
            #pragma unroll
            for (int kx = 0; kx < 3; kx++) {
                m9[ky*3 + kx] = mh[ky] * mw[kx];
                off[ky*3 + kx] = ihx[ky]*W2 + iwx[kx];
            }

        float acc[64];
        #pragma unroll
        for (int o = 0; o < 64; o++) acc[o] = b3[o];

        const float* inb = in + (size_t)b * F2_PB;
        for (int c = 0; c < 64; c++) {
            const float* g = inb + (size_t)c * (H2*W2);
            const float* w9 = dw3 + c*9;
            float dv = 0.f;
            #pragma unroll
            for (int p = 0; p < 9; p++)
                dv = fmaf(w9[p], m9[p] * g[off[p]], dv);
            const float* wr = wb + W_PW3T + c*64;
            #pragma unroll
            for (int o = 0; o < 64; o++) acc[o] = fmaf(wr[o], dv, acc[o]);
        }

        size_t obase = ((size_t)b * 64) * (H3*W3) + (size_t)oh*W3 + ow;
        #pragma unroll
        for (int o = 0; o < 64; o++) {
            float v = acc[o];
            out[obase + (size_t)o*(H3*W3)] = v > 0.f ? v : (__expf(v) - 1.f);
        }
    }
}

// ---------------- K4: attention pool + MLP + GRU head -----------------------
__global__ __launch_bounds__(1024) void k_head(
    const float* __restrict__ f3,
    const float* __restrict__ attn_w, const float* __restrict__ attn_b,
    const float* __restrict__ mlp1_w, const float* __restrict__ mlp1_b,
    const float* __restrict__ mlp2_w, const float* __restrict__ mlp2_b,
    const float* __restrict__ w_ih, const float* __restrict__ b_ih,
    const float* __restrict__ b_hh,
    const float* __restrict__ fc_w, const float* __restrict__ fc_b,
    float* __restrict__ out)
{
    const int N  = H3 * W3;   // 4800
    const int N4 = N / 4;     // 1200
    __shared__ float s_w[H3 * W3];
    __shared__ float s_attn[64];
    __shared__ float s_redm[16];
    __shared__ float s_reds[16];
    __shared__ float s_inv[1];
    __shared__ float s_pooled[64];
    __shared__ float s_h1[32];
    __shared__ float s_om[3];
    __shared__ float s_h[32];

    int t = threadIdx.x, b = blockIdx.x;
    int lane = t & 63, wid = t >> 6;   // 16 waves
    if (t < 64) s_attn[t] = attn_w[t];
    __syncthreads();

    const float4* fb4 = (const float4*)(f3 + (size_t)b * F3_PB);
    float ab = attn_b[0];

    float lmax = -1e30f;
    for (int n4 = t; n4 < N4; n4 += 1024) {
        float4 l = make_float4(ab, ab, ab, ab);
        #pragma unroll 8
        for (int c = 0; c < 64; c++) {
            float4 v = fb4[c * N4 + n4];
            float a = s_attn[c];
            l.x = fmaf(a, v.x, l.x); l.y = fmaf(a, v.y, l.y);
            l.z = fmaf(a, v.z, l.z); l.w = fmaf(a, v.w, l.w);
        }
        ((float4*)s_w)[n4] = l;
        lmax = fmaxf(lmax, fmaxf(fmaxf(l.x, l.y), fmaxf(l.z, l.w)));
    }
    #pragma unroll
    for (int off = 32; off; off >>= 1) lmax = fmaxf(lmax, __shfl_down(lmax, off, 64));
    if (lane == 0) s_redm[wid] = lmax;
    __syncthreads();
    {
        float m = s_redm[0];
        #pragma unroll
        for (int i = 1; i < 16; i++) m = fmaxf(m, s_redm[i]);
        lmax = m;
    }

    float lsum = 0.f;
    for (int n = t; n < N; n += 1024) { float e = __expf(s_w[n] - lmax); s_w[n] = e; lsum += e; }
    #pragma unroll
    for (int off = 32; off; off >>= 1) lsum += __shfl_down(lsum, off, 64);
    if (lane == 0) s_reds[wid] = lsum;
    __syncthreads();
    if (t == 0) {
        float s = 0.f;
        #pragma unroll
        for (int i = 0; i < 16; i++) s += s_reds[i];
        s_inv[0] = 1.f / s;
    }
    __syncthreads();
    float invS = s_inv[0];

    const float4* sw4 = (const float4*)s_w;
    for (int c = wid; c < 64; c += 16) {
        float s = 0.f;
        for (int i = lane; i < N4; i += 64) {
            float4 v = fb4[c * N4 + i];
            float4 w = sw4[i];
            s = fmaf(v.x, w.x, s); s = fmaf(v.y, w.y, s);
            s = fmaf(v.z, w.z, s); s = fmaf(v.w, w.w, s);
        }
        #pragma unroll
        for (int off = 32; off; off >>= 1) s += __shfl_down(s, off, 64);
        if (lane == 0) s_pooled[c] = s * invS;
    }
    __syncthreads();

    if (t < 32) {
        float a = mlp1_b[t];
        #pragma unroll 8
        for (int c = 0; c < 64; c++) a = fmaf(mlp1_w[t*64 + c], s_pooled[c], a);
        s_h1[t] = a > 0.f ? a : (__expf(a) - 1.f);
    }
    __syncthreads();
    if (t < 3) {
        float a = mlp2_b[t];
        for (int j = 0; j < 32; j++) a = fmaf(mlp2_w[t*32 + j], s_h1[j], a);
        s_om[t] = a;
    }
    __syncthreads();
    if (t < 32) {
        float gr = b_ih[t], gz = b_ih[32 + t], gn = b_ih[64 + t];
        #pragma unroll
        for (int k = 0; k < 3; k++) {
            float ok = s_om[k];
            gr = fmaf(w_ih[t*3 + k],        ok, gr);
            gz = fmaf(w_ih[(32 + t)*3 + k], ok, gz);
            gn = fmaf(w_ih[(64 + t)*3 + k], ok, gn);
        }
        float hr = b_hh[t], hz = b_hh[32 + t], hn = b_hh[64 + t];
        float r = 1.f / (1.f + __expf(-(gr + hr)));
        float z = 1.f / (1.f + __expf(-(gz + hz)));
        float nn = tanhf(gn + r * hn);
        s_h[t] = (1.f - z) * nn;
    }
    __syncthreads();
    if (t < 3) {
        float dl = fc_b[t];
        for (int j = 0; j < 32; j++) dl = fmaf(fc_w[t*32 + j], s_h[j], dl);
        out[b*3 + t] = s_om[t] + dl;
    }
}

// ---------------- host ----------------
extern "C" void kernel_launch(void* const* d_in, const int* in_sizes, int n_in,
                              void* d_out, int out_size, void* d_ws, size_t ws_size,
                              hipStream_t stream)
{
    const float* flow = (const float*)d_in[0];
    float* wb = (float*)d_ws;

    // layout: [wbuf][f2 all 32 batches][f3 all 32 batches] = 196.7 MB (ws >= 275 MB)
    float* f2 = (float*)((char*)d_ws + WBUF_BYTES);
    float* f3 = f2 + (size_t)32 * F2_PB;

    k_cvt<<<1, 256, 0, stream>>>(
        (const float*)d_in[2], (const float*)d_in[5], (const float*)d_in[8], wb);

    // fused stage1+stage2: one thread per f2 pixel
    k_fuse12<<<(32*H2*W2)/256, 256, 0, stream>>>(
        flow, (const float*)d_in[1], (const float*)d_in[3],
        (const float*)d_in[4], (const float*)d_in[6], wb, f2);

    // stage3: one thread per f3 pixel
    k_stage3<<<(32*H3*W3)/256, 256, 0, stream>>>(
        f2, (const float*)d_in[7], (const float*)d_in[9], wb, f3);

    k_head<<<32, 1024, 0, stream>>>(f3,
        (const float*)d_in[10], (const float*)d_in[11],
        (const float*)d_in[12], (const float*)d_in[13],
        (const float*)d_in[14], (const float*)d_in[15],
        (const float*)d_in[16], (const float*)d_in[18],
        (const float*)d_in[19], (const float*)d_in[20],
        (const float*)d_in[21], (float*)d_out);
}

// Round 2
// 328.326 us; speedup vs baseline: 1.1211x; 1.1211x over previous
//
#include <hip/hip_runtime.h>
#include <hip/hip_bf16.h>

#define H0 480
#define W0 640
#define H1 240
#define W1 320
#define H2 120
#define W2 160
#define H3 60
#define W3 80

// fp32 weight buffer offsets (in floats) inside d_ws  (transposed pointwise copies)
#define W_PW1T  0      // 5*32  [cin*32+o]
#define W_PW2T  160    // 32*64 [cin*64+o]
#define W_PW3T  2208   // 64*64 [cin*64+o]
#define WBUF_BYTES 65536

#define F2_PB (64 * H2 * W2)   // 1,228,800
#define F3_PB (64 * H3 * W3)   //   307,200

// k_fuse12 tiling: each block computes a 32x8 f2-pixel tile via a shared f1 tile.
#define TH 8           // f2 tile height
#define TW 32          // f2 tile width
#define TILES_W 5      // W2/TW
#define TILES_H 15     // H2/TH
#define TILES_PB 75    // per batch
#define F1COLS 65      // 2*TW+1
#define NP 1105        // 17*65 f1 pixels per tile
#define LROW 66        // swizzled LDS row stride (33 even + 33 odd cols)
#define LCH 1122       // 17*66 floats per channel

typedef float v2f __attribute__((ext_vector_type(2)));

// ---------------- K0: transpose pointwise weights ---------------------------
__global__ __launch_bounds__(256) void k_cvt(
    const float* __restrict__ pw1, const float* __restrict__ pw2,
    const float* __restrict__ pw3, float* __restrict__ wb)
{
    int t = threadIdx.x;
    for (int i = t; i < 160;  i += 256) { int o = i / 5,  c = i % 5;  wb[W_PW1T + c*32 + o] = pw1[i]; }
    for (int i = t; i < 2048; i += 256) { int o = i >> 5, c = i & 31; wb[W_PW2T + c*64 + o] = pw2[i]; }
    for (int i = t; i < 4096; i += 256) { int o = i >> 6, c = i & 63; wb[W_PW3T + c*64 + o] = pw3[i]; }
}

// ---------------- K12: fused stage1+stage2, LDS-shared f1 tile ---------------
// Phase A: 256 threads cooperatively compute d[5] (dw1 outputs) for the 17x65
//          f1 tile (5 pixels/thread, registers).
// Per 8-channel chunk:
//   A2: pw1+ELU -> f1 activations into LDS (invalid f1 pixels stored as 0).
//   B : each thread (1 f2 pixel) does dw2 from LDS (9 ds_reads, swizzled
//       conflict-free layout) + packed-fp32 rank-1 pw2 update of acc2[32].
// Removes the 2.25x redundant f1 recompute, all interior boundary-mask
// arithmetic, and the 162 scattered global taps/thread of the old version.
__global__ __launch_bounds__(256, 3) void k_fuse12(
    const float* __restrict__ flow, const float* __restrict__ dw1,
    const float* __restrict__ b1, const float* __restrict__ dw2,
    const float* __restrict__ b2, const float* __restrict__ wb,
    float* __restrict__ out)
{
    __shared__ float f1buf[8 * LCH];   // 35,904 B

    const int t = threadIdx.x;
    const int bid = blockIdx.x;
    const int b = bid / TILES_PB;
    const int tile = bid - b * TILES_PB;
    const int oh0 = (tile / TILES_W) * TH;
    const int ow0 = (tile % TILES_W) * TW;

    const float sx = 2.f / (W0 - 1), sy = 2.f / (H0 - 1);

    // ---- uniform closed-form coefficients for coord-channel convs ----
    // conv(linear/quadratic field) is linear/quadratic in position.
    float cs2[3], rs3[3], cs4[3], rs4[3];
    #pragma unroll
    for (int k = 0; k < 3; k++) {
        cs2[k] = dw1[18+k]   + dw1[21+k]   + dw1[24+k];
        rs3[k] = dw1[27+3*k] + dw1[28+3*k] + dw1[29+3*k];
        cs4[k] = dw1[36+k]   + dw1[39+k]   + dw1[42+k];
        rs4[k] = dw1[36+3*k] + dw1[37+3*k] + dw1[38+3*k];
    }
    const float ax2 = 2.f * sx, ay2 = 2.f * sy;
    float ex[3], fyc[3];
    #pragma unroll
    for (int k = 0; k < 3; k++) { ex[k] = sx*(float)(k-1) - 1.f; fyc[k] = sy*(float)(k-1) - 1.f; }
    const float AX1 = ax2*(cs2[0]+cs2[1]+cs2[2]);
    const float AX0 = cs2[0]*ex[0]+cs2[1]*ex[1]+cs2[2]*ex[2];
    const float AY1 = ay2*(rs3[0]+rs3[1]+rs3[2]);
    const float AY0 = rs3[0]*fyc[0]+rs3[1]*fyc[1]+rs3[2]*fyc[2];
    const float GX2 = ax2*ax2*(cs4[0]+cs4[1]+cs4[2]);
    const float GX1 = 2.f*ax2*(cs4[0]*ex[0]+cs4[1]*ex[1]+cs4[2]*ex[2]);
    const float GX0 = cs4[0]*ex[0]*ex[0]+cs4[1]*ex[1]*ex[1]+cs4[2]*ex[2]*ex[2];
    const float GY2 = ay2*ay2*(rs4[0]+rs4[1]+rs4[2]);
    const float GY1 = 2.f*ay2*(rs4[0]*fyc[0]+rs4[1]*fyc[1]+rs4[2]*fyc[2]);
    const float GY0 = rs4[0]*fyc[0]*fyc[0]+rs4[1]*fyc[1]*fyc[1]+rs4[2]*fyc[2]*fyc[2];

    // ---- Phase A: d-vectors for 5 f1 pixels/thread ----
    float dd[5][5];
    float vmf[5];
    int   widx[5];
    const float* fb0 = flow + (size_t)(b*2) * (H0*W0);
    const float* fb1 = fb0 + (size_t)(H0*W0);

    #pragma unroll
    for (int i = 0; i < 5; i++) {
        int p = t + i*256; if (p > NP-1) p = NP-1;      // only i==4 clamps
        int tr = p / F1COLS;
        int tc = p - tr * F1COLS;
        widx[i] = tr*LROW + (tc & 1)*33 + (tc >> 1);    // parity-split swizzle
        int fr = 2*oh0 - 1 + tr;
        int fc = 2*ow0 - 1 + tc;
        vmf[i] = (fr >= 0 && fc >= 0) ? 1.f : 0.f;
        if (fr >= 1 && fc >= 1) {
            // interior: mask-free taps + closed-form coords
            const float* r0 = fb0 + (size_t)(2*fr - 1) * W0 + (2*fc - 1);
            const float* r1 = fb1 + (size_t)(2*fr - 1) * W0 + (2*fc - 1);
            float a0 = 0.f, a1 = 0.f;
            #pragma unroll
            for (int ky = 0; ky < 3; ky++)
                #pragma unroll
                for (int kx = 0; kx < 3; kx++) {
                    a0 = fmaf(dw1[ky*3+kx],   r0[ky*W0+kx], a0);
                    a1 = fmaf(dw1[9+ky*3+kx], r1[ky*W0+kx], a1);
                }
            dd[i][0] = a0; dd[i][1] = a1;
            float fcf = (float)fc, frf = (float)fr;
            dd[i][2] = fmaf(AX1, fcf, AX0);
            dd[i][3] = fmaf(AY1, frf, AY0);
            dd[i][4] = fmaf(fmaf(GX2, fcf, GX1), fcf, GX0)
                     + fmaf(fmaf(GY2, frf, GY1), frf, GY0);
        } else {
            // border: original general masked path
            int frc = fr < 0 ? 0 : fr, fcc = fc < 0 ? 0 : fc;
            int ih0 = 2*frc - 1, iw0 = 2*fcc - 1;
            float mh[3] = { ih0 >= 0 ? 1.f : 0.f, 1.f, 1.f };
            float mw[3] = { iw0 >= 0 ? 1.f : 0.f, 1.f, 1.f };
            int ihx[3] = { ih0 < 0 ? 0 : ih0, ih0 + 1, ih0 + 2 };
            int iwx[3] = { iw0 < 0 ? 0 : iw0, iw0 + 1, iw0 + 2 };
            float a0 = 0.f, a1 = 0.f;
            #pragma unroll
            for (int ky = 0; ky < 3; ky++) {
                const float* rp0 = fb0 + (size_t)ihx[ky] * W0;
                const float* rp1 = fb1 + (size_t)ihx[ky] * W0;
                #pragma unroll
                for (int kx = 0; kx < 3; kx++) {
                    float m = mh[ky]*mw[kx];
                    a0 = fmaf(dw1[ky*3+kx],   m * rp0[iwx[kx]], a0);
                    a1 = fmaf(dw1[9+ky*3+kx], m * rp1[iwx[kx]], a1);
                }
            }
            dd[i][0] = a0; dd[i][1] = a1;
            float axv = 0.f, ayv = 0.f, arv = 0.f;
            #pragma unroll
            for (int ky = 0; ky < 3; ky++) {
                float yv = fmaf((float)(ih0 + ky), sy, -1.f);
                #pragma unroll
                for (int kx = 0; kx < 3; kx++) {
                    float xv = fmaf((float)(iw0 + kx), sx, -1.f);
                    float m = mh[ky]*mw[kx];
                    axv = fmaf(dw1[18 + ky*3 + kx], m * xv, axv);
                    ayv = fmaf(dw1[27 + ky*3 + kx], m * yv, ayv);
                    arv = fmaf(dw1[36 + ky*3 + kx], m * (xv*xv + yv*yv), arv);
                }
            }
            dd[i][2] = axv; dd[i][3] = ayv; dd[i][4] = arv;
        }
    }

    // ---- chunked A2 (f1 -> LDS) + B (dw2 + pw2) ----
    v2f acc2[32];
    #pragma unroll
    for (int o = 0; o < 32; o++) acc2[o] = *(const v2f*)(b2 + 2*o);

    const int lr = t >> 5, lc = t & 31;        // this thread's f2 pixel in tile
    const int rbase = 2*lr*LROW + lc;          // swizzled LDS base for taps

    for (int cc = 0; cc < 4; cc++) {
        #pragma unroll
        for (int j = 0; j < 8; j++) {
            int c = cc*8 + j;
            float w10 = wb[W_PW1T + c];
            float w11 = wb[W_PW1T + 32 + c];
            float w12 = wb[W_PW1T + 64 + c];
            float w13 = wb[W_PW1T + 96 + c];
            float w14 = wb[W_PW1T + 128 + c];
            float bc = b1[c];
            #pragma unroll
            for (int i = 0; i < 5; i++) {
                float v = bc;
                v = fmaf(w10, dd[i][0], v);
                v = fmaf(w11, dd[i][1], v);
                v = fmaf(w12, dd[i][2], v);
                v = fmaf(w13, dd[i][3], v);
                v = fmaf(w14, dd[i][4], v);
                float f = v > 0.f ? v : (__expf(v) - 1.f);
                f *= vmf[i];                       // invalid f1 pixel -> 0
                if (i < 4)               f1buf[j*LCH + widx[i]] = f;
                else if (t < NP - 1024)  f1buf[j*LCH + widx[4]] = f;   // t < 81
            }
        }
        __syncthreads();
        #pragma unroll
        for (int j = 0; j < 8; j++) {
            int c = cc*8 + j;
            const float* w9 = dw2 + c*9;               // uniform
            const float* fp = f1buf + j*LCH + rbase;
            float dv = 0.f;
            #pragma unroll
            for (int r = 0; r < 3; r++) {
                // tap cols 2*lc+{0,1,2} -> swizzled offsets {0, 33, 1}
                dv = fmaf(w9[r*3+0], fp[r*LROW],      dv);
                dv = fmaf(w9[r*3+1], fp[r*LROW + 33], dv);
                dv = fmaf(w9[r*3+2], fp[r*LROW + 1],  dv);
            }
            const v2f* wr2 = (const v2f*)(wb + W_PW2T + c*64);  // uniform
            v2f dvv = { dv, dv };
            #pragma unroll
            for (int o = 0; o < 32; o++)
                acc2[o] = __builtin_elementwise_fma(wr2[o], dvv, acc2[o]);  // v_pk_fma_f32
        }
        __syncthreads();
    }

    const int oh = oh0 + lr, ow = ow0 + lc;
    size_t obase = ((size_t)b * 64) * (H2*W2) + (size_t)oh * W2 + ow;
    #pragma unroll
    for (int o = 0; o < 32; o++) {
        float va = acc2[o].x, vb2 = acc2[o].y;
        out[obase + (size_t)(2*o)   * (H2*W2)] = va  > 0.f ? va  : (__expf(va)  - 1.f);
        out[obase + (size_t)(2*o+1) * (H2*W2)] = vb2 > 0.f ? vb2 : (__expf(vb2) - 1.f);
    }
}

// ---------------- K3: dwsep3 + ELU, register-direct (round-0 known-good) ----
__global__ __launch_bounds__(256, 4) void k_stage3(
    const float* __restrict__ in, const float* __restrict__ dw3,
    const float* __restrict__ b3, const float* __restrict__ wb,
    float* __restrict__ out)
{
    int idx = blockIdx.x * 256 + threadIdx.x;     // 153,600 exact
    int ow = idx % W3; int tmp = idx / W3; int oh = tmp % H3; int b = tmp / H3;
    int ih0 = 2*oh - 1, iw0 = 2*ow - 1;
    float mh[3] = { ih0 >= 0 ? 1.f : 0.f, 1.f, 1.f };
    float mw[3] = { iw0 >= 0 ? 1.f : 0.f, 1.f, 1.f };
    int ihx[3] = { ih0 < 0 ? 0 : ih0, ih0 + 1, ih0 + 2 };
    int iwx[3] = { iw0 < 0 ? 0 : iw0, iw0 + 1, iw0 + 2 };
    float m9[9];
    int off[9];
    #pragma unroll
    for (int ky = 0; ky < 3; ky++)
        #pragma unroll
        for (int kx = 0; kx < 3; kx++) {
            m9[ky*3 + kx] = mh[ky] * mw[kx];
            off[ky*3 + kx] = ihx[ky]*W2 + iwx[kx];
        }

    float acc[64];
    #pragma unroll
    for (int o = 0; o < 64; o++) acc[o] = b3[o];

    const float* inb = in + (size_t)b * F2_PB;
    for (int c = 0; c < 64; c++) {
        const float* g = inb + (size_t)c * (H2*W2);
        const float* w9 = dw3 + c*9;               // uniform
        float dv = 0.f;
        #pragma unroll
        for (int p = 0; p < 9; p++)
            dv = fmaf(w9[p], m9[p] * g[off[p]], dv);
        const float* wr = wb + W_PW3T + c*64;      // uniform
        #pragma unroll
        for (int o = 0; o < 64; o++) acc[o] = fmaf(wr[o], dv, acc[o]);
    }

    size_t obase = ((size_t)b * 64) * (H3*W3) + (size_t)oh*W3 + ow;
    #pragma unroll
    for (int o = 0; o < 64; o++) {
        float v = acc[o];
        out[obase + (size_t)o*(H3*W3)] = v > 0.f ? v : (__expf(v) - 1.f);
    }
}

// ---------------- K4: attention pool + MLP + GRU head -----------------------
__global__ __launch_bounds__(1024) void k_head(
    const float* __restrict__ f3,
    const float* __restrict__ attn_w, const float* __restrict__ attn_b,
    const float* __restrict__ mlp1_w, const float* __restrict__ mlp1_b,
    const float* __restrict__ mlp2_w, const float* __restrict__ mlp2_b,
    const float* __restrict__ w_ih, const float* __restrict__ b_ih,
    const float* __restrict__ b_hh,
    const float* __restrict__ fc_w, const float* __restrict__ fc_b,
    float* __restrict__ out)
{
    const int N  = H3 * W3;   // 4800
    const int N4 = N / 4;     // 1200
    __shared__ float s_w[H3 * W3];
    __shared__ float s_attn[64];
    __shared__ float s_redm[16];
    __shared__ float s_reds[16];
    __shared__ float s_inv[1];
    __shared__ float s_pooled[64];
    __shared__ float s_h1[32];
    __shared__ float s_om[3];
    __shared__ float s_h[32];

    int t = threadIdx.x, b = blockIdx.x;
    int lane = t & 63, wid = t >> 6;   // 16 waves
    if (t < 64) s_attn[t] = attn_w[t];
    __syncthreads();

    const float4* fb4 = (const float4*)(f3 + (size_t)b * F3_PB);
    float ab = attn_b[0];

    float lmax = -1e30f;
    for (int n4 = t; n4 < N4; n4 += 1024) {
        float4 l = make_float4(ab, ab, ab, ab);
        #pragma unroll 8
        for (int c = 0; c < 64; c++) {
            float4 v = fb4[c * N4 + n4];
            float a = s_attn[c];
            l.x = fmaf(a, v.x, l.x); l.y = fmaf(a, v.y, l.y);
            l.z = fmaf(a, v.z, l.z); l.w = fmaf(a, v.w, l.w);
        }
        ((float4*)s_w)[n4] = l;
        lmax = fmaxf(lmax, fmaxf(fmaxf(l.x, l.y), fmaxf(l.z, l.w)));
    }
    #pragma unroll
    for (int off = 32; off; off >>= 1) lmax = fmaxf(lmax, __shfl_down(lmax, off, 64));
    if (lane == 0) s_redm[wid] = lmax;
    __syncthreads();
    {
        float m = s_redm[0];
        #pragma unroll
        for (int i = 1; i < 16; i++) m = fmaxf(m, s_redm[i]);
        lmax = m;
    }

    float lsum = 0.f;
    for (int n = t; n < N; n += 1024) { float e = __expf(s_w[n] - lmax); s_w[n] = e; lsum += e; }
    #pragma unroll
    for (int off = 32; off; off >>= 1) lsum += __shfl_down(lsum, off, 64);
    if (lane == 0) s_reds[wid] = lsum;
    __syncthreads();
    if (t == 0) {
        float s = 0.f;
        #pragma unroll
        for (int i = 0; i < 16; i++) s += s_reds[i];
        s_inv[0] = 1.f / s;
    }
    __syncthreads();
    float invS = s_inv[0];

    const float4* sw4 = (const float4*)s_w;
    for (int c = wid; c < 64; c += 16) {
        float s = 0.f;
        for (int i = lane; i < N4; i += 64) {
            float4 v = fb4[c * N4 + i];
            float4 w = sw4[i];
            s = fmaf(v.x, w.x, s); s = fmaf(v.y, w.y, s);
            s = fmaf(v.z, w.z, s); s = fmaf(v.w, w.w, s);
        }
        #pragma unroll
        for (int off = 32; off; off >>= 1) s += __shfl_down(s, off, 64);
        if (lane == 0) s_pooled[c] = s * invS;
    }
    __syncthreads();

    if (t < 32) {
        float a = mlp1_b[t];
        #pragma unroll 8
        for (int c = 0; c < 64; c++) a = fmaf(mlp1_w[t*64 + c], s_pooled[c], a);
        s_h1[t] = a > 0.f ? a : (__expf(a) - 1.f);
    }
    __syncthreads();
    if (t < 3) {
        float a = mlp2_b[t];
        for (int j = 0; j < 32; j++) a = fmaf(mlp2_w[t*32 + j], s_h1[j], a);
        s_om[t] = a;
    }
    __syncthreads();
    if (t < 32) {
        float gr = b_ih[t], gz = b_ih[32 + t], gn = b_ih[64 + t];
        #pragma unroll
        for (int k = 0; k < 3; k++) {
            float ok = s_om[k];
            gr = fmaf(w_ih[t*3 + k],        ok, gr);
            gz = fmaf(w_ih[(32 + t)*3 + k], ok, gz);
            gn = fmaf(w_ih[(64 + t)*3 + k], ok, gn);
        }
        float hr = b_hh[t], hz = b_hh[32 + t], hn = b_hh[64 + t];
        float r = 1.f / (1.f + __expf(-(gr + hr)));
        float z = 1.f / (1.f + __expf(-(gz + hz)));
        float nn = tanhf(gn + r * hn);
        s_h[t] = (1.f - z) * nn;
    }
    __syncthreads();
    if (t < 3) {
        float dl = fc_b[t];
        for (int j = 0; j < 32; j++) dl = fmaf(fc_w[t*32 + j], s_h[j], dl);
        out[b*3 + t] = s_om[t] + dl;
    }
}

// ---------------- host ----------------
extern "C" void kernel_launch(void* const* d_in, const int* in_sizes, int n_in,
                              void* d_out, int out_size, void* d_ws, size_t ws_size,
                              hipStream_t stream)
{
    const float* flow = (const float*)d_in[0];
    float* wb = (float*)d_ws;

    // layout: [wbuf][f2 all 32 batches][f3 all 32 batches] = 196.7 MB (ws >= 275 MB)
    float* f2 = (float*)((char*)d_ws + WBUF_BYTES);
    float* f3 = f2 + (size_t)32 * F2_PB;

    k_cvt<<<1, 256, 0, stream>>>(
        (const float*)d_in[2], (const float*)d_in[5], (const float*)d_in[8], wb);

    // fused stage1+stage2: one block per 32x8 f2 tile
    k_fuse12<<<32 * TILES_PB, 256, 0, stream>>>(
        flow, (const float*)d_in[1], (const float*)d_in[3],
        (const float*)d_in[4], (const float*)d_in[6], wb, f2);

    // stage3: one thread per f3 pixel
    k_stage3<<<(32*H3*W3)/256, 256, 0, stream>>>(
        f2, (const float*)d_in[7], (const float*)d_in[9], wb, f3);

    k_head<<<32, 1024, 0, stream>>>(f3,
        (const float*)d_in[10], (const float*)d_in[11],
        (const float*)d_in[12], (const float*)d_in[13],
        (const float*)d_in[14], (const float*)d_in[15],
        (const float*)d_in[16], (const float*)d_in[18],
        (const float*)d_in[19], (const float*)d_in[20],
        (const float*)d_in[21], (float*)d_out);
}